// Round 4
// baseline (1148.272 us; speedup 1.0000x reference)
//
#include <hip/hip_runtime.h>

#define N_NODES  50000
#define N_EDGES  800000
#define N_GRAPHS 64

typedef unsigned short u16x8 __attribute__((ext_vector_type(8)));

__device__ __forceinline__ float bf2f(unsigned short h) {
    return __uint_as_float((unsigned)h << 16);
}
__device__ __forceinline__ unsigned short f2bf(float f) {
    unsigned u = __float_as_uint(f);
    unsigned r = (u + 0x7FFFu + ((u >> 16) & 1u)) >> 16;   // RNE
    return (unsigned short)r;
}

// ---------------- utility kernels ----------------

__global__ void zero_int_kernel(int* __restrict__ p, int n) {
    for (int i = blockIdx.x * blockDim.x + threadIdx.x; i < n; i += gridDim.x * blockDim.x)
        p[i] = 0;
}

// in-degree histogram (int)
__global__ void hist_kernel(const int* __restrict__ ei, int* __restrict__ cnt) {
    const int* dst = ei + N_EDGES;
    for (int e = blockIdx.x * blockDim.x + threadIdx.x; e < N_EDGES; e += gridDim.x * blockDim.x)
        atomicAdd(&cnt[dst[e]], 1);
}

__global__ void dinv_kernel(const int* __restrict__ cnt, float* __restrict__ dinv) {
    for (int i = blockIdx.x * blockDim.x + threadIdx.x; i < N_NODES; i += gridDim.x * blockDim.x)
        dinv[i] = rsqrtf((float)cnt[i] + 1.f);   // +1 self-loop
}

// single-block exclusive scan of cnt -> rowptr; also resets cnt to 0 (fill counters)
__global__ __launch_bounds__(1024) void scan_kernel(int* __restrict__ cnt, int* __restrict__ rowptr) {
    __shared__ int part[1024];
    const int CH = 49;                      // 1024*49 = 50176 >= N_NODES
    int t = threadIdx.x;
    int base = t * CH;
    int s = 0;
    for (int i = 0; i < CH; ++i) {
        int idx = base + i;
        if (idx < N_NODES) s += cnt[idx];
    }
    part[t] = s;
    __syncthreads();
    for (int off = 1; off < 1024; off <<= 1) {
        int v = (t >= off) ? part[t - off] : 0;
        __syncthreads();
        part[t] += v;
        __syncthreads();
    }
    int run = (t == 0) ? 0 : part[t - 1];
    for (int i = 0; i < CH; ++i) {
        int idx = base + i;
        if (idx < N_NODES) {
            int c = cnt[idx];
            rowptr[idx] = run;
            run += c;
            cnt[idx] = 0;                   // reset for fill pass
        }
    }
    if (t == 1023) rowptr[N_NODES] = run;
}

// place edges into CSR slots; pack (src, weight) as int2
__global__ void fill_kernel(const int* __restrict__ ei, const int* __restrict__ rowptr,
                            int* __restrict__ fill, const float* __restrict__ dinv,
                            int2* __restrict__ csr) {
    const int* src = ei;
    const int* dst = ei + N_EDGES;
    for (int e = blockIdx.x * blockDim.x + threadIdx.x; e < N_EDGES; e += gridDim.x * blockDim.x) {
        int s = src[e], d = dst[e];
        int pos = rowptr[d] + atomicAdd(&fill[d], 1);
        csr[pos] = make_int2(s, __float_as_int(dinv[s] * dinv[d]));
    }
}

// nodes-per-graph histogram (float)
__global__ void gcount_kernel(const int* __restrict__ batch, float* __restrict__ cntg) {
    for (int i = blockIdx.x * blockDim.x + threadIdx.x; i < N_NODES; i += gridDim.x * blockDim.x)
        atomicAdd(&cntg[batch[i]], 1.f);
}

// ---------------- GEMM: C[M,128] = A[M,K] @ B[K,128], fp32 math, bf16 out ----------------
template<int K>
__global__ __launch_bounds__(256) void gemm_n128(const float* __restrict__ A,
                                                 const float* __restrict__ B,
                                                 unsigned short* __restrict__ C, int M) {
    constexpr int BK = 16;
    __shared__ float As[BK][68];
    __shared__ float Bs[BK][132];

    const int tid = threadIdx.x;
    const int tx  = tid & 31;
    const int ty  = tid >> 5;
    const int row0 = blockIdx.x * 64;

    const int lar = tid >> 2;
    const int lak = (tid & 3) * 4;
    const int lbk = tid >> 4;
    const int lbc = (tid & 15) * 8;

    float acc[8][4];
    #pragma unroll
    for (int i = 0; i < 8; ++i)
        #pragma unroll
        for (int j = 0; j < 4; ++j) acc[i][j] = 0.f;

    int arow = row0 + lar;
    if (arow >= M) arow = M - 1;
    const float* Aptr = A + (long)arow * K + lak;
    const float* Bptr = B + (long)lbk * 128 + lbc;

    for (int k0 = 0; k0 < K; k0 += BK) {
        float4 av = *(const float4*)(Aptr + k0);
        As[lak + 0][lar] = av.x;
        As[lak + 1][lar] = av.y;
        As[lak + 2][lar] = av.z;
        As[lak + 3][lar] = av.w;
        float4 bv0 = *(const float4*)(Bptr + (long)k0 * 128);
        float4 bv1 = *(const float4*)(Bptr + (long)k0 * 128 + 4);
        *(float4*)&Bs[lbk][lbc]     = bv0;
        *(float4*)&Bs[lbk][lbc + 4] = bv1;
        __syncthreads();
        #pragma unroll
        for (int kk = 0; kk < BK; ++kk) {
            float4 b4 = *(const float4*)&Bs[kk][tx * 4];
            float4 a0 = *(const float4*)&As[kk][ty * 8];
            float4 a1 = *(const float4*)&As[kk][ty * 8 + 4];
            float a[8] = {a0.x, a0.y, a0.z, a0.w, a1.x, a1.y, a1.z, a1.w};
            float b[4] = {b4.x, b4.y, b4.z, b4.w};
            #pragma unroll
            for (int i = 0; i < 8; ++i)
                #pragma unroll
                for (int j = 0; j < 4; ++j)
                    acc[i][j] = fmaf(a[i], b[j], acc[i][j]);
        }
        __syncthreads();
    }

    #pragma unroll
    for (int i = 0; i < 8; ++i) {
        int r = row0 + ty * 8 + i;
        if (r < M) {
            ushort4 v;
            v.x = f2bf(acc[i][0]); v.y = f2bf(acc[i][1]);
            v.z = f2bf(acc[i][2]); v.w = f2bf(acc[i][3]);
            *(ushort4*)(C + (long)r * 128 + tx * 4) = v;
        }
    }
}

// ---------------- CSR gather (bf16 rows): one wave per node ----------------
// Lane layout: es = lane>>3 (edge slot 0..7), cl = lane&7 (16 channels per lane).
// Unroll 2 -> 16 rows (16 x 256B bf16 reads) in flight per wave.
// MODE 0: out[node] = relu(agg + bias)  (fp32, feeds GEMM2)
// MODE 1: z = dot(relu(agg + bias), Wl); zsum[batch[node]] += z
template<int MODE>
__global__ __launch_bounds__(256) void gather_kernel(
        const unsigned short* __restrict__ xl, const float* __restrict__ dinv,
        const int* __restrict__ rowptr, const int2* __restrict__ csr,
        const float* __restrict__ bias, float* __restrict__ outbuf,
        const float* __restrict__ Wl, const int* __restrict__ batch,
        float* __restrict__ zsum) {
    int node = blockIdx.x * 4 + (threadIdx.x >> 6);
    if (node >= N_NODES) return;
    const int lane = threadIdx.x & 63;
    const int es = lane >> 3;      // edge slot 0..7
    const int cl = lane & 7;       // channel lane
    const int c0 = cl * 16;        // 16 channels per lane

    const int start = rowptr[node];
    const int end   = rowptr[node + 1];

    // self-loop row (issue early)
    float di = dinv[node];
    const u16x8* selfp = (const u16x8*)(xl + (long)node * 128 + c0);
    u16x8 sv0 = selfp[0];
    u16x8 sv1 = selfp[1];

    float accA[16], accB[16];
    #pragma unroll
    for (int j = 0; j < 16; ++j) { accA[j] = 0.f; accB[j] = 0.f; }

    for (int eb = start; eb < end; eb += 16) {
        int eA = eb + es;
        int eB = eA + 8;
        int eAc = (eA < end) ? eA : start;
        int eBc = (eB < end) ? eB : start;
        int2 cA = csr[eAc];
        int2 cB = csr[eBc];
        float wA = (eA < end) ? __int_as_float(cA.y) : 0.f;
        float wB = (eB < end) ? __int_as_float(cB.y) : 0.f;
        const u16x8* rA = (const u16x8*)(xl + (long)cA.x * 128 + c0);
        const u16x8* rB = (const u16x8*)(xl + (long)cB.x * 128 + c0);
        u16x8 a0 = rA[0], a1 = rA[1];
        u16x8 b0 = rB[0], b1 = rB[1];
        #pragma unroll
        for (int j = 0; j < 8; ++j) {
            accA[j]     = fmaf(wA, bf2f(a0[j]), accA[j]);
            accA[j + 8] = fmaf(wA, bf2f(a1[j]), accA[j + 8]);
            accB[j]     = fmaf(wB, bf2f(b0[j]), accB[j]);
            accB[j + 8] = fmaf(wB, bf2f(b1[j]), accB[j + 8]);
        }
    }

    float s[16];
    #pragma unroll
    for (int j = 0; j < 16; ++j) s[j] = accA[j] + accB[j];

    // reduce across the 8 edge slots (lane bits 3,4,5)
    #pragma unroll
    for (int j = 0; j < 16; ++j) {
        s[j] += __shfl_xor(s[j], 8);
        s[j] += __shfl_xor(s[j], 16);
        s[j] += __shfl_xor(s[j], 32);
    }

    // self-loop + bias + relu (identical on all es lanes)
    float w2 = di * di;
    #pragma unroll
    for (int j = 0; j < 8; ++j) {
        s[j]     = fmaxf(fmaf(w2, bf2f(sv0[j]), s[j])     + bias[c0 + j],     0.f);
        s[j + 8] = fmaxf(fmaf(w2, bf2f(sv1[j]), s[j + 8]) + bias[c0 + 8 + j], 0.f);
    }

    if (MODE == 0) {
        if (es == 0) {
            float* op = outbuf + (long)node * 128 + c0;
            #pragma unroll
            for (int q = 0; q < 4; ++q) {
                float4 o = make_float4(s[q*4], s[q*4+1], s[q*4+2], s[q*4+3]);
                *(float4*)(op + q * 4) = o;
            }
        }
    } else {
        float z = 0.f;
        #pragma unroll
        for (int j = 0; j < 16; ++j) z = fmaf(s[j], Wl[c0 + j], z);
        // sum across the 8 channel lanes (bits 0,1,2); es groups hold duplicates
        z += __shfl_xor(z, 1);
        z += __shfl_xor(z, 2);
        z += __shfl_xor(z, 4);
        if (lane == 0)
            atomicAdd(&zsum[batch[node]], z);
    }
}

__global__ void out_kernel(const float* __restrict__ zsum, const float* __restrict__ cntg,
                           const float* __restrict__ bl, float* __restrict__ out) {
    int g = threadIdx.x;
    if (g < N_GRAPHS) out[g] = zsum[g] / fmaxf(cntg[g], 1.f) + bl[0];
}

// ---------------- launch ----------------

extern "C" void kernel_launch(void* const* d_in, const int* in_sizes, int n_in,
                              void* d_out, int out_size, void* d_ws, size_t ws_size,
                              hipStream_t stream) {
    const float* x    = (const float*)d_in[0];
    const int*   ei   = (const int*)d_in[1];
    const int*   batch= (const int*)d_in[2];
    const float* W1   = (const float*)d_in[3];
    const float* b1   = (const float*)d_in[4];
    const float* W2   = (const float*)d_in[5];
    const float* b2   = (const float*)d_in[6];
    const float* Wl   = (const float*)d_in[7];
    const float* bl   = (const float*)d_in[8];
    float* out = (float*)d_out;

    // workspace layout (4B words)
    float* ws      = (float*)d_ws;
    float* dinv    = ws;                         // 50176
    float* zsum    = ws + 50176;                 // 64
    float* cntg    = ws + 50176 + 64;            // 64
    int*   cnt_i   = (int*)(ws + 50304);         // 50176 (also fill counters)
    int*   rowptr  = (int*)(ws + 100480);        // 50176 (50001 used)
    int2*  csr     = (int2*)(ws + 150656);       // 800000 int2
    unsigned short* xl16 = (unsigned short*)(ws + 1750656);  // 6.4M bf16 (12.8 MB)
    float* h1      = ws + 1750656 + 3200000;     // 6.4M fp32 (GEMM2 input)

    // zero zsum, cntg, cnt_i in one pass (contiguous)
    zero_int_kernel<<<128, 256, 0, stream>>>((int*)(ws + 50176), 128 + 50176);

    hist_kernel<<<1024, 256, 0, stream>>>(ei, cnt_i);
    dinv_kernel<<<128, 256, 0, stream>>>(cnt_i, dinv);
    scan_kernel<<<1, 1024, 0, stream>>>(cnt_i, rowptr);
    fill_kernel<<<1024, 256, 0, stream>>>(ei, rowptr, cnt_i, dinv, csr);
    gcount_kernel<<<256, 256, 0, stream>>>(batch, cntg);

    // layer 1
    gemm_n128<768><<<782, 256, 0, stream>>>(x, W1, xl16, N_NODES);
    gather_kernel<0><<<12500, 256, 0, stream>>>(xl16, dinv, rowptr, csr,
                                                b1, h1, nullptr, nullptr, nullptr);
    // layer 2 + pool
    gemm_n128<128><<<782, 256, 0, stream>>>(h1, W2, xl16, N_NODES);
    gather_kernel<1><<<12500, 256, 0, stream>>>(xl16, dinv, rowptr, csr,
                                                b2, nullptr, Wl, batch, zsum);

    out_kernel<<<1, 64, 0, stream>>>(zsum, cntg, bl, out);
}

// Round 5
// 1079.784 us; speedup vs baseline: 1.0634x; 1.0634x over previous
//
#include <hip/hip_runtime.h>

#define N_NODES  50000
#define N_EDGES  800000
#define N_GRAPHS 64

typedef unsigned short u16x8 __attribute__((ext_vector_type(8)));

__device__ __forceinline__ float bf2f(unsigned short h) {
    return __uint_as_float((unsigned)h << 16);
}
__device__ __forceinline__ unsigned short f2bf(float f) {
    unsigned u = __float_as_uint(f);
    unsigned r = (u + 0x7FFFu + ((u >> 16) & 1u)) >> 16;   // RNE
    return (unsigned short)r;
}

// ---------------- utility kernels ----------------

__global__ void zero_int_kernel(int* __restrict__ p, int n) {
    for (int i = blockIdx.x * blockDim.x + threadIdx.x; i < n; i += gridDim.x * blockDim.x)
        p[i] = 0;
}

// in-degree histogram (int)
__global__ void hist_kernel(const int* __restrict__ ei, int* __restrict__ cnt) {
    const int* dst = ei + N_EDGES;
    for (int e = blockIdx.x * blockDim.x + threadIdx.x; e < N_EDGES; e += gridDim.x * blockDim.x)
        atomicAdd(&cnt[dst[e]], 1);
}

__global__ void dinv_kernel(const int* __restrict__ cnt, float* __restrict__ dinv) {
    for (int i = blockIdx.x * blockDim.x + threadIdx.x; i < N_NODES; i += gridDim.x * blockDim.x)
        dinv[i] = rsqrtf((float)cnt[i] + 1.f);   // +1 self-loop
}

// single-block exclusive scan of cnt -> rowptr; also resets cnt to 0 (fill counters)
__global__ __launch_bounds__(1024) void scan_kernel(int* __restrict__ cnt, int* __restrict__ rowptr) {
    __shared__ int part[1024];
    const int CH = 49;                      // 1024*49 = 50176 >= N_NODES
    int t = threadIdx.x;
    int base = t * CH;
    int s = 0;
    for (int i = 0; i < CH; ++i) {
        int idx = base + i;
        if (idx < N_NODES) s += cnt[idx];
    }
    part[t] = s;
    __syncthreads();
    for (int off = 1; off < 1024; off <<= 1) {
        int v = (t >= off) ? part[t - off] : 0;
        __syncthreads();
        part[t] += v;
        __syncthreads();
    }
    int run = (t == 0) ? 0 : part[t - 1];
    for (int i = 0; i < CH; ++i) {
        int idx = base + i;
        if (idx < N_NODES) {
            int c = cnt[idx];
            rowptr[idx] = run;
            run += c;
            cnt[idx] = 0;                   // reset for fill pass
        }
    }
    if (t == 1023) rowptr[N_NODES] = run;
}

// place edges into CSR slots; pack (src, weight) as int2
__global__ void fill_kernel(const int* __restrict__ ei, const int* __restrict__ rowptr,
                            int* __restrict__ fill, const float* __restrict__ dinv,
                            int2* __restrict__ csr) {
    const int* src = ei;
    const int* dst = ei + N_EDGES;
    for (int e = blockIdx.x * blockDim.x + threadIdx.x; e < N_EDGES; e += gridDim.x * blockDim.x) {
        int s = src[e], d = dst[e];
        int pos = rowptr[d] + atomicAdd(&fill[d], 1);
        csr[pos] = make_int2(s, __float_as_int(dinv[s] * dinv[d]));
    }
}

// nodes-per-graph histogram (float)
__global__ void gcount_kernel(const int* __restrict__ batch, float* __restrict__ cntg) {
    for (int i = blockIdx.x * blockDim.x + threadIdx.x; i < N_NODES; i += gridDim.x * blockDim.x)
        atomicAdd(&cntg[batch[i]], 1.f);
}

// ---------------- GEMM: C[M,128] = A[M,K] @ B[K,128], fp32 math, bf16 out ----------------
template<int K>
__global__ __launch_bounds__(256) void gemm_n128(const float* __restrict__ A,
                                                 const float* __restrict__ B,
                                                 unsigned short* __restrict__ C, int M) {
    constexpr int BK = 16;
    __shared__ float As[BK][68];
    __shared__ float Bs[BK][132];

    const int tid = threadIdx.x;
    const int tx  = tid & 31;
    const int ty  = tid >> 5;
    const int row0 = blockIdx.x * 64;

    const int lar = tid >> 2;
    const int lak = (tid & 3) * 4;
    const int lbk = tid >> 4;
    const int lbc = (tid & 15) * 8;

    float acc[8][4];
    #pragma unroll
    for (int i = 0; i < 8; ++i)
        #pragma unroll
        for (int j = 0; j < 4; ++j) acc[i][j] = 0.f;

    int arow = row0 + lar;
    if (arow >= M) arow = M - 1;
    const float* Aptr = A + (long)arow * K + lak;
    const float* Bptr = B + (long)lbk * 128 + lbc;

    for (int k0 = 0; k0 < K; k0 += BK) {
        float4 av = *(const float4*)(Aptr + k0);
        As[lak + 0][lar] = av.x;
        As[lak + 1][lar] = av.y;
        As[lak + 2][lar] = av.z;
        As[lak + 3][lar] = av.w;
        float4 bv0 = *(const float4*)(Bptr + (long)k0 * 128);
        float4 bv1 = *(const float4*)(Bptr + (long)k0 * 128 + 4);
        *(float4*)&Bs[lbk][lbc]     = bv0;
        *(float4*)&Bs[lbk][lbc + 4] = bv1;
        __syncthreads();
        #pragma unroll
        for (int kk = 0; kk < BK; ++kk) {
            float4 b4 = *(const float4*)&Bs[kk][tx * 4];
            float4 a0 = *(const float4*)&As[kk][ty * 8];
            float4 a1 = *(const float4*)&As[kk][ty * 8 + 4];
            float a[8] = {a0.x, a0.y, a0.z, a0.w, a1.x, a1.y, a1.z, a1.w};
            float b[4] = {b4.x, b4.y, b4.z, b4.w};
            #pragma unroll
            for (int i = 0; i < 8; ++i)
                #pragma unroll
                for (int j = 0; j < 4; ++j)
                    acc[i][j] = fmaf(a[i], b[j], acc[i][j]);
        }
        __syncthreads();
    }

    #pragma unroll
    for (int i = 0; i < 8; ++i) {
        int r = row0 + ty * 8 + i;
        if (r < M) {
            ushort4 v;
            v.x = f2bf(acc[i][0]); v.y = f2bf(acc[i][1]);
            v.z = f2bf(acc[i][2]); v.w = f2bf(acc[i][3]);
            *(ushort4*)(C + (long)r * 128 + tx * 4) = v;
        }
    }
}

// ---------------- CSR gather (bf16 rows): persistent waves, grid-stride ----------------
// Lane layout: es = lane>>3 (edge slot 0..7), cl = lane&7 (16 channels per lane).
// Each wave loops over nodes with stride = total waves; next node's rowptr is
// prefetched one iteration ahead so the metadata chain overlaps accumulation.
// MODE 0: out[node] = relu(agg + bias)  (fp32, feeds GEMM2)
// MODE 1: z = dot(relu(agg + bias), Wl); zsum[batch[node]] += z
#define GATHER_BLOCKS 2048
template<int MODE>
__global__ __launch_bounds__(256) void gather_kernel(
        const unsigned short* __restrict__ xl, const float* __restrict__ dinv,
        const int* __restrict__ rowptr, const int2* __restrict__ csr,
        const float* __restrict__ bias, float* __restrict__ outbuf,
        const float* __restrict__ Wl, const int* __restrict__ batch,
        float* __restrict__ zsum) {
    const int lane = threadIdx.x & 63;
    const int es = lane >> 3;      // edge slot 0..7
    const int cl = lane & 7;       // channel lane
    const int c0 = cl * 16;        // 16 channels per lane

    const int wave   = blockIdx.x * 4 + (threadIdx.x >> 6);
    const int nwaves = GATHER_BLOCKS * 4;

    // bias/Wl are tiny and uniform per lane: hoist out of node loop
    float bv[16];
    #pragma unroll
    for (int j = 0; j < 16; ++j) bv[j] = bias[c0 + j];
    float wlv[16];
    if (MODE == 1) {
        #pragma unroll
        for (int j = 0; j < 16; ++j) wlv[j] = Wl[c0 + j];
    }

    int node = wave;
    if (node >= N_NODES) return;
    int start = rowptr[node];
    int end   = rowptr[node + 1];

    for (; node < N_NODES; ) {
        // prefetch next node's metadata (overlaps with this node's work)
        int nxt = node + nwaves;
        int n_start = 0, n_end = 0;
        if (nxt < N_NODES) {
            n_start = rowptr[nxt];
            n_end   = rowptr[nxt + 1];
        }

        float di = dinv[node];
        const u16x8* selfp = (const u16x8*)(xl + (long)node * 128 + c0);
        u16x8 sv0 = selfp[0];
        u16x8 sv1 = selfp[1];

        float accA[16], accB[16];
        #pragma unroll
        for (int j = 0; j < 16; ++j) { accA[j] = 0.f; accB[j] = 0.f; }

        for (int eb = start; eb < end; eb += 16) {
            int eA = eb + es;
            int eB = eA + 8;
            int eAc = (eA < end) ? eA : start;
            int eBc = (eB < end) ? eB : start;
            int2 cA = csr[eAc];
            int2 cB = csr[eBc];
            float wA = (eA < end) ? __int_as_float(cA.y) : 0.f;
            float wB = (eB < end) ? __int_as_float(cB.y) : 0.f;
            const u16x8* rA = (const u16x8*)(xl + (long)cA.x * 128 + c0);
            const u16x8* rB = (const u16x8*)(xl + (long)cB.x * 128 + c0);
            u16x8 a0 = rA[0], a1 = rA[1];
            u16x8 b0 = rB[0], b1 = rB[1];
            #pragma unroll
            for (int j = 0; j < 8; ++j) {
                accA[j]     = fmaf(wA, bf2f(a0[j]), accA[j]);
                accA[j + 8] = fmaf(wA, bf2f(a1[j]), accA[j + 8]);
                accB[j]     = fmaf(wB, bf2f(b0[j]), accB[j]);
                accB[j + 8] = fmaf(wB, bf2f(b1[j]), accB[j + 8]);
            }
        }

        float s[16];
        #pragma unroll
        for (int j = 0; j < 16; ++j) s[j] = accA[j] + accB[j];

        // reduce across the 8 edge slots (lane bits 3,4,5)
        #pragma unroll
        for (int j = 0; j < 16; ++j) {
            s[j] += __shfl_xor(s[j], 8);
            s[j] += __shfl_xor(s[j], 16);
            s[j] += __shfl_xor(s[j], 32);
        }

        // self-loop + bias + relu (identical on all es lanes)
        float w2 = di * di;
        #pragma unroll
        for (int j = 0; j < 8; ++j) {
            s[j]     = fmaxf(fmaf(w2, bf2f(sv0[j]), s[j])     + bv[j],     0.f);
            s[j + 8] = fmaxf(fmaf(w2, bf2f(sv1[j]), s[j + 8]) + bv[j + 8], 0.f);
        }

        if (MODE == 0) {
            if (es == 0) {
                float* op = outbuf + (long)node * 128 + c0;
                #pragma unroll
                for (int q = 0; q < 4; ++q) {
                    float4 o = make_float4(s[q*4], s[q*4+1], s[q*4+2], s[q*4+3]);
                    *(float4*)(op + q * 4) = o;
                }
            }
        } else {
            float z = 0.f;
            #pragma unroll
            for (int j = 0; j < 16; ++j) z = fmaf(s[j], wlv[j], z);
            z += __shfl_xor(z, 1);
            z += __shfl_xor(z, 2);
            z += __shfl_xor(z, 4);
            if (lane == 0)
                atomicAdd(&zsum[batch[node]], z);
        }

        node = nxt;
        start = n_start;
        end = n_end;
    }
}

__global__ void out_kernel(const float* __restrict__ zsum, const float* __restrict__ cntg,
                           const float* __restrict__ bl, float* __restrict__ out) {
    int g = threadIdx.x;
    if (g < N_GRAPHS) out[g] = zsum[g] / fmaxf(cntg[g], 1.f) + bl[0];
}

// ---------------- launch ----------------

extern "C" void kernel_launch(void* const* d_in, const int* in_sizes, int n_in,
                              void* d_out, int out_size, void* d_ws, size_t ws_size,
                              hipStream_t stream) {
    const float* x    = (const float*)d_in[0];
    const int*   ei   = (const int*)d_in[1];
    const int*   batch= (const int*)d_in[2];
    const float* W1   = (const float*)d_in[3];
    const float* b1   = (const float*)d_in[4];
    const float* W2   = (const float*)d_in[5];
    const float* b2   = (const float*)d_in[6];
    const float* Wl   = (const float*)d_in[7];
    const float* bl   = (const float*)d_in[8];
    float* out = (float*)d_out;

    // workspace layout (4B words)
    float* ws      = (float*)d_ws;
    float* dinv    = ws;                         // 50176
    float* zsum    = ws + 50176;                 // 64
    float* cntg    = ws + 50176 + 64;            // 64
    int*   cnt_i   = (int*)(ws + 50304);         // 50176 (also fill counters)
    int*   rowptr  = (int*)(ws + 100480);        // 50176 (50001 used)
    int2*  csr     = (int2*)(ws + 150656);       // 800000 int2
    unsigned short* xl16 = (unsigned short*)(ws + 1750656);  // 6.4M bf16 (12.8 MB)
    float* h1      = ws + 1750656 + 3200000;     // 6.4M fp32 (GEMM2 input)

    // zero zsum, cntg, cnt_i in one pass (contiguous)
    zero_int_kernel<<<128, 256, 0, stream>>>((int*)(ws + 50176), 128 + 50176);

    hist_kernel<<<1024, 256, 0, stream>>>(ei, cnt_i);
    dinv_kernel<<<128, 256, 0, stream>>>(cnt_i, dinv);
    scan_kernel<<<1, 1024, 0, stream>>>(cnt_i, rowptr);
    fill_kernel<<<1024, 256, 0, stream>>>(ei, rowptr, cnt_i, dinv, csr);
    gcount_kernel<<<256, 256, 0, stream>>>(batch, cntg);

    // layer 1
    gemm_n128<768><<<782, 256, 0, stream>>>(x, W1, xl16, N_NODES);
    gather_kernel<0><<<GATHER_BLOCKS, 256, 0, stream>>>(xl16, dinv, rowptr, csr,
                                                b1, h1, nullptr, nullptr, nullptr);
    // layer 2 + pool
    gemm_n128<128><<<782, 256, 0, stream>>>(h1, W2, xl16, N_NODES);
    gather_kernel<1><<<GATHER_BLOCKS, 256, 0, stream>>>(xl16, dinv, rowptr, csr,
                                                b2, nullptr, Wl, batch, zsum);

    out_kernel<<<1, 64, 0, stream>>>(zsum, cntg, bl, out);
}